// Round 6
// baseline (145.262 us; speedup 1.0000x reference)
//
#include <hip/hip_runtime.h>
#include <hip/hip_fp16.h>

#define Bsz 8
#define Cn  4
#define Hn  64
#define Wn  2048
#define HW  (Hn*Wn)

#define TW 64
#define TH 16
#define BLK 512
// 3-iteration cone: +/-3 rows, +/-6 cols
#define BW 76
#define BH 22
#define NB (BW*BH)          // 1672
// region-1 (iter-1 output region): 72 x 20 at tile-local (-2,-4)
#define R1W 72
#define R1H 20
#define NP1 (R1W*(R1H/2))   // 720 vertical pixel-pairs

// Gaussian stencil exp(-(dh^2+dw^2)/(2*0.9^2)), center zeroed.
#define G1 0.53940824f
#define G2 0.29096127f
#define G4 0.08465836f
#define G5 0.04566536f

struct Half4 { __half2 lo, hi; };
struct Beta { __half2 t[14]; __half2 mk; };   // (px0,px1) packed per tap

__device__ __forceinline__ float Gw(int r, int d) {
    const float Gt[3][5] = {{G5,G2,G1,G2,G5},{G4,G1,0.f,G1,G4},{G5,G2,G1,G2,G5}};
    return Gt[r][d];
}
__device__ __forceinline__ constexpr int tap_of(int r, int d) {
    return (r == 0) ? d : (r == 1) ? ((d < 2) ? 5 + d : 4 + d) : 9 + d;
}

// beta*mask tap weights for one vertical pixel-pair, from staged (xyz,mask).
__device__ __forceinline__ void compute_beta(int pair, const float4* __restrict__ X,
                                             Beta& B) {
    const int pr = pair / R1W;
    const int pc = pair - pr * R1W;
    const int bx0 = (2 * pr + 1) * BW + pc + 2;
    const float4 xc0 = X[bx0];
    const float4 xc1 = X[bx0 + BW];
    float bm0[14], bm1[14];
#pragma unroll
    for (int j = 0; j < 4; ++j) {
        const int rb = bx0 + (j - 1) * BW;
#pragma unroll
        for (int d = 0; d < 5; ++d) {
            const float4 xn = X[rb + d - 2];
            if (j <= 2 && !(j == 1 && d == 2)) {
                float dx = xn.x - xc0.x, dy = xn.y - xc0.y, dz = xn.z - xc0.z;
                bm0[tap_of(j, d)] = __expf(-2222.2222f * (dx*dx + dy*dy + dz*dz)) * xn.w;
            }
            if (j >= 1 && !(j == 2 && d == 2)) {
                float dx = xn.x - xc1.x, dy = xn.y - xc1.y, dz = xn.z - xc1.z;
                bm1[tap_of(j - 1, d)] = __expf(-2222.2222f * (dx*dx + dy*dy + dz*dz)) * xn.w;
            }
        }
    }
#pragma unroll
    for (int t = 0; t < 14; ++t) B.t[t] = __floats2half2_rn(bm0[t], bm1[t]);
    B.mk = __floats2half2_rn(xc0.w, xc1.w);
}

template<bool FINAL>
__device__ __forceinline__ void finish_one(int gh, int gw, int bi,
        __half2 ka, __half2 kb, __half2 aa, __half2 ab, float mc,
        const float* __restrict__ unary, float* __restrict__ outp,
        Half4* __restrict__ Sout, size_t qbase,
        const float* wa, const float* wsm, const float* cw, bool store_ok) {
    if (FINAL && !store_ok) return;
    const bool inimg = FINAL || ((gh >= 0) & (gh < Hn) & (gw >= 0) & (gw < Wn));
    if (inimg) {
        size_t p = (size_t)gh * Wn + gw;
        float ksm[4] = {__low2float(ka), __high2float(ka), __low2float(kb), __high2float(kb)};
        float app[4] = {__low2float(aa), __high2float(aa), __low2float(ab), __high2float(ab)};
        float wk[4];
#pragma unroll
        for (int c = 0; c < 4; ++c)
            wk[c] = ksm[c] * (wsm[c] + wa[c] * (app[c] * mc));
        float q[4];
#pragma unroll
        for (int o = 0; o < 4; ++o) {
            float pw = cw[o*4+0]*wk[0] + cw[o*4+1]*wk[1] + cw[o*4+2]*wk[2] + cw[o*4+3]*wk[3];
            q[o] = unary[qbase + p + (size_t)o * HW] - pw;
        }
        if (FINAL) {
#pragma unroll
            for (int o = 0; o < 4; ++o)
                outp[qbase + p + (size_t)o * HW] = q[o];
        } else {
            float mx = fmaxf(fmaxf(q[0], q[1]), fmaxf(q[2], q[3]));
            float e0 = __expf(q[0]-mx), e1 = __expf(q[1]-mx);
            float e2 = __expf(q[2]-mx), e3 = __expf(q[3]-mx);
            float inv = 1.0f / (e0 + e1 + e2 + e3);
            Half4 s; s.lo = __floats2half2_rn(e0*inv, e1*inv);
            s.hi = __floats2half2_rn(e2*inv, e3*inv);
            Sout[bi] = s;
        }
    } else if (!FINAL) {
        Half4 z; z.lo = __float2half2_rn(0.f); z.hi = z.lo;
        Sout[bi] = z;
    }
}

template<bool FINAL>
__device__ __forceinline__ void do_pair(int pair, const Half4* __restrict__ Sin,
        Half4* __restrict__ Sout, const Beta& B,
        const float* __restrict__ unary, float* __restrict__ outp,
        size_t qbase, int h0, int w0,
        const float* wa, const float* wsm, const float* cw) {
    const int pr = pair / R1W;
    const int pc = pair - pr * R1W;
    const int bx0 = (2 * pr + 1) * BW + pc + 2;

    const __half2 z2 = __float2half2_rn(0.f);
    __half2 k0a=z2,k0b=z2,a0a=z2,a0b=z2,k1a=z2,k1b=z2,a1a=z2,a1b=z2;

#pragma unroll
    for (int j = 0; j < 4; ++j) {
        const int rb = bx0 + (j - 1) * BW;
        Half4 s[5];
#pragma unroll
        for (int d = 0; d < 5; ++d) s[d] = Sin[rb + d - 2];
#pragma unroll
        for (int d = 0; d < 5; ++d) {
            if (j <= 2 && !(j == 1 && d == 2)) {          // px0: dh = j-1
                const int t = tap_of(j, d);
                const __half2 g2 = __float2half2_rn(Gw(j, d));
                k0a = __hfma2(g2, s[d].lo, k0a);
                k0b = __hfma2(g2, s[d].hi, k0b);
                const __half2 bm2 = __half2half2(__low2half(B.t[t]));
                a0a = __hfma2(bm2, s[d].lo, a0a);
                a0b = __hfma2(bm2, s[d].hi, a0b);
            }
            if (j >= 1 && !(j == 2 && d == 2)) {          // px1: dh = j-2
                const int t = tap_of(j - 1, d);
                const __half2 g2 = __float2half2_rn(Gw(j - 1, d));
                k1a = __hfma2(g2, s[d].lo, k1a);
                k1b = __hfma2(g2, s[d].hi, k1b);
                const __half2 bm2 = __half2half2(__high2half(B.t[t]));
                a1a = __hfma2(bm2, s[d].lo, a1a);
                a1b = __hfma2(bm2, s[d].hi, a1b);
            }
        }
    }

    const int gw = w0 + pc - 4;
    const int gh0 = h0 + 2 * pr - 2;
    const bool ok = (pr >= 1) & (pr <= 8) & (pc >= 4) & (pc <= 67);  // region3
    finish_one<FINAL>(gh0,     gw, bx0,      k0a, k0b, a0a, a0b, __low2float(B.mk),
                      unary, outp, Sout, qbase, wa, wsm, cw, ok);
    finish_one<FINAL>(gh0 + 1, gw, bx0 + BW, k1a, k1b, a1a, a1b, __high2float(B.mk),
                      unary, outp, Sout, qbase, wa, wsm, cw, ok);
}

__global__ __launch_bounds__(BLK, 4) void crf_fused(const float* __restrict__ unary,
                                                    const float* __restrict__ xyz,
                                                    const float* __restrict__ mask,
                                                    const float* __restrict__ wa_g,
                                                    const float* __restrict__ wsm_g,
                                                    const float* __restrict__ cw_g,
                                                    float* __restrict__ outp) {
    __shared__ __align__(16) unsigned char LDS_[NB * 16];   // 26752 B
    Half4*  SA   = (Half4*)LDS_;                // [0, NB*8)
    Half4*  SB   = (Half4*)(LDS_ + NB * 8);     // [NB*8, NB*16)
    float4* XBUF = (float4*)LDS_;               // overlays SA+SB, phases 1-2 only

    const int tid = threadIdx.x;
    const int w0 = blockIdx.x * TW;
    const int h0 = blockIdx.y * TH;
    const int b  = blockIdx.z;

    const size_t qbase = (size_t)b * Cn * HW;
    const size_t xbase = (size_t)b * 3 * HW;
    const size_t mbase = (size_t)b * HW;

    float wa[4], wsm[4], cw[16];
#pragma unroll
    for (int k = 0; k < 4; ++k) { wa[k] = wa_g[k]; wsm[k] = wsm_g[k]; }
#pragma unroll
    for (int k = 0; k < 16; ++k) cw[k] = cw_g[k];

    // ---- phase 1: stage packed (xyz, mask) cone halo into XBUF ----
    for (int i = tid; i < NB; i += BLK) {
        int br = i / BW, bc = i - br * BW;
        int gh = h0 + br - 3, gw = w0 + bc - 6;
        float4 xm = make_float4(0.f, 0.f, 0.f, 0.f);
        if (gh >= 0 && gh < Hn && gw >= 0 && gw < Wn) {
            size_t p = (size_t)gh * Wn + gw;
            xm = make_float4(xyz[xbase + p], xyz[xbase + p + HW],
                             xyz[xbase + p + 2 * HW], mask[mbase + p]);
        }
        XBUF[i] = xm;
    }
    __syncthreads();

    // ---- phase 2: iteration-invariant beta*mask into REGISTERS ----
    Beta B0, B1;
    compute_beta(tid, XBUF, B0);
    const bool t2 = tid < (NP1 - BLK);          // 208 threads take a 2nd pair
    if (t2) compute_beta(tid + BLK, XBUF, B1);
    __syncthreads();

    // ---- phase 3: SA = softmax(unary) staged fp16x4 over NB; SB ring-zeroed ----
    for (int i = tid; i < NB; i += BLK) {
        int br = i / BW, bc = i - br * BW;
        int gh = h0 + br - 3, gw = w0 + bc - 6;
        Half4 s; s.lo = __float2half2_rn(0.f); s.hi = s.lo;
        if (gh >= 0 && gh < Hn && gw >= 0 && gw < Wn) {
            size_t p = (size_t)gh * Wn + gw;
            float q0 = unary[qbase + p];
            float q1 = unary[qbase + p + HW];
            float q2 = unary[qbase + p + 2 * HW];
            float q3 = unary[qbase + p + 3 * HW];
            float mx = fmaxf(fmaxf(q0, q1), fmaxf(q2, q3));
            float e0 = __expf(q0 - mx), e1 = __expf(q1 - mx);
            float e2 = __expf(q2 - mx), e3 = __expf(q3 - mx);
            float inv = 1.0f / (e0 + e1 + e2 + e3);
            s.lo = __floats2half2_rn(e0 * inv, e1 * inv);
            s.hi = __floats2half2_rn(e2 * inv, e3 * inv);
        }
        SA[i] = s;
        Half4 z; z.lo = __float2half2_rn(0.f); z.hi = z.lo;
        SB[i] = z;
    }
    __syncthreads();

    // ---- iter 1: SA -> SB (fixed pixel ownership, full region-1) ----
    do_pair<false>(tid, SA, SB, B0, unary, nullptr, qbase, h0, w0, wa, wsm, cw);
    if (t2) do_pair<false>(tid + BLK, SA, SB, B1, unary, nullptr, qbase, h0, w0, wa, wsm, cw);
    __syncthreads();
    // ---- iter 2: SB -> SA ----
    do_pair<false>(tid, SB, SA, B0, unary, nullptr, qbase, h0, w0, wa, wsm, cw);
    if (t2) do_pair<false>(tid + BLK, SB, SA, B1, unary, nullptr, qbase, h0, w0, wa, wsm, cw);
    __syncthreads();
    // ---- iter 3: SA -> out (store only region-3 == the tile) ----
    do_pair<true>(tid, SA, nullptr, B0, unary, outp, qbase, h0, w0, wa, wsm, cw);
    if (t2) do_pair<true>(tid + BLK, SA, nullptr, B1, unary, outp, qbase, h0, w0, wa, wsm, cw);
}

extern "C" void kernel_launch(void* const* d_in, const int* in_sizes, int n_in,
                              void* d_out, int out_size, void* d_ws, size_t ws_size,
                              hipStream_t stream) {
    const float* unary  = (const float*)d_in[0];
    const float* xyz    = (const float*)d_in[1];
    const float* mask   = (const float*)d_in[2];
    const float* wa     = (const float*)d_in[3];
    const float* wsm    = (const float*)d_in[4];
    const float* compat = (const float*)d_in[5];
    float* outp = (float*)d_out;

    dim3 grid(Wn / TW, Hn / TH, Bsz), blk(BLK);
    crf_fused<<<grid, blk, 0, stream>>>(unary, xyz, mask, wa, wsm, compat, outp);
}